// Round 7
// baseline (328.458 us; speedup 1.0000x reference)
//
#include <hip/hip_runtime.h>

#define NN 2048
#define PITCH 72  // u16 elems per LDS row: 144B -> 16B-aligned rows

typedef __attribute__((ext_vector_type(8))) _Float16 half8;  // 8 fp16 = 4 VGPRs (MFMA A/B frag)
typedef __attribute__((ext_vector_type(4))) float floatx4;   // MFMA C/D frag

static_assert(sizeof(half8) == 16, "");

#define MRINIT -3.0e38f

__device__ __forceinline__ unsigned short f2h(float f) {
    union { _Float16 h; unsigned short u; } v;
    v.h = (_Float16)f;  // RNE
    return v.u;
}
__device__ __forceinline__ float h2f(unsigned short u) {
    union { unsigned short u; _Float16 h; } v;
    v.u = u;
    return (float)v.h;
}
__device__ __forceinline__ unsigned int pk2h(float a, float b) {  // v_cvt_pkrtz_f16_f32
    union { __fp16 __attribute__((ext_vector_type(2))) h; unsigned int u; } v;
    v.h = __builtin_amdgcn_cvt_pkrtz(a, b);
    return v.u;
}

// ---------- mask = (graph + I) > 0, packed to bits: mbits[i*64 + w] bit b = mask[i][w*32+b] ----------
__global__ __launch_bounds__(256) void mask_kernel(const int* __restrict__ graph,
                                                   unsigned int* __restrict__ mbits) {
    const int t = threadIdx.x;
    const int lane = t & 63;
    const int W = (blockIdx.x << 2) + (t >> 6);  // wave id, 0..65535
    const int i = W >> 5;                        // row 0..2047
    const int cb = W & 31;                       // 64-col chunk
    const int j = (cb << 6) + lane;
    const int g = graph[(size_t)i * NN + j];
    const unsigned long long bal = __ballot((g > 0) || (i == j));
    if (lane == 0)  mbits[(i << 6) + (cb << 1)]     = (unsigned int)bal;
    if (lane == 32) mbits[(i << 6) + (cb << 1) + 1] = (unsigned int)(bal >> 32);
}

// ---------- h[b,h,n,d] = sum_c x[b,n,c] * Wh[h,d,c]  (fp32 in, fp16 out) ----------
__global__ __launch_bounds__(256) void proj_kernel(const float* __restrict__ x,
                                                   const float* __restrict__ Wh,
                                                   unsigned short* __restrict__ hout) {
    __shared__ float xs[16 * 64];   // 4 KB
    __shared__ float wsh[64 * 65];  // 16.25 KB, pad 65 -> conflict-free
    const int t = threadIdx.x;
    const int pair = blockIdx.x >> 7;  // b*4 + hh
    const int nt = blockIdx.x & 127;
    const int n0 = nt << 4;
    const int b = pair >> 2;
    const int hh = pair & 3;
    const float* xb = x + (((size_t)b * NN + n0) << 6);
    for (int i = t; i < 1024; i += 256) xs[i] = xb[i];
    const float* wb = Wh + (hh << 12);
    for (int i = t; i < 4096; i += 256) wsh[(i >> 6) * 65 + (i & 63)] = wb[i];
    __syncthreads();
    const int d = t & 63;
    const int q = t >> 6;
    float a0 = 0.f, a1 = 0.f, a2 = 0.f, a3 = 0.f;
    for (int c = 0; c < 64; ++c) {
        const float w = wsh[d * 65 + c];
        a0 += xs[(((q << 2) + 0) << 6) + c] * w;
        a1 += xs[(((q << 2) + 1) << 6) + c] * w;
        a2 += xs[(((q << 2) + 2) << 6) + c] * w;
        a3 += xs[(((q << 2) + 3) << 6) + c] * w;
    }
    unsigned short* ho = hout + (((size_t)pair * NN + n0 + (q << 2)) << 6) + d;
    ho[0]   = f2h(a0);
    ho[64]  = f2h(a1);
    ho[128] = f2h(a2);
    ho[192] = f2h(a3);
}

// ---------- fused GAT layer: Out[mat,n,:] = softmax_mask(H H^T)[n,:] @ H + bias ----------
// 4 waves/block, 64 q-rows/block, K-tiles of 64, flash online softmax, exp2 domain.
// QK A-frags read DIRECT from global (wave-coalesced 2KB pattern, L1-resident).
// Kts (transposed V) double-buffered in LDS -> ONE barrier per iter. Ps is per-wave
// private (same-wave DS ordering + compiler fence; no barrier).
// OUTMODE 0: fp16 out with leaky pre-applied (feeds mix). OUTMODE 1: fused
// leaky+LayerNorm, fp32 out (final output).
template <int OUTMODE>
__global__ __launch_bounds__(256) void gat_flash(const unsigned short* __restrict__ Hm,
                                                 const unsigned int* __restrict__ mbits,
                                                 const float* __restrict__ bias,
                                                 const int bias_mod,
                                                 const float* __restrict__ gamma,
                                                 const float* __restrict__ beta,
                                                 void* __restrict__ OutP) {
    __shared__ unsigned short Kts[2][64 * PITCH];  // transposed K/V tile [d][j], XOR-swizzled, dbuf
    __shared__ unsigned short Ps[4 * 16 * PITCH];  // per-wave P [m][j], XOR-swizzled by m&7

    const int t = threadIdx.x;
    const int wave = t >> 6;
    const int lane = t & 63;
    const int quad = lane >> 4;
    const int m = lane & 15;

    const int mat = blockIdx.x >> 5;  // qtiles = 32
    const int qt = blockIdx.x & 31;
    const int q0 = qt << 6;

    const unsigned short* Hb = Hm + ((size_t)mat << 17);  // mat * 2048 * 64
    const int gq = q0 + (wave << 4) + m;                  // this lane's q-row

    // Q B-frags, loaded once; scale by log2(e) so softmax uses exp2 (exact identity)
    half8 bq0 = *(const half8*)(Hb + (gq << 6) + (quad << 3));
    half8 bq1 = *(const half8*)(Hb + (gq << 6) + 32 + (quad << 3));
    const _Float16 LOG2E = (_Float16)1.44269504f;
    bq0 = bq0 * LOG2E;
    bq1 = bq1 * LOG2E;

    const int boff = (mat % bias_mod) << 6;
    const float bv0 = bias[boff + m];
    const float bv1 = bias[boff + 16 + m];
    const float bv2 = bias[boff + 32 + m];
    const float bv3 = bias[boff + 48 + m];

    // A-frag global base: lane reads H[krow][8quad..+8); krow varies by kt/jt
    const unsigned short* arow = Hb + (m << 6) + (quad << 3);

    // staging assignment: thread -> rows {2p, 2p+1}, d-chunk cc
    const int p = t >> 3;
    const int cc = t & 7;
    const int jch = p >> 2;         // j-chunk for transposed writes
    const int jo = (p & 3) << 1;    // u16 offset within 8-elem chunk

    float mr = MRINIT;
    float lr = 0.f;
    floatx4 O0 = {0.f, 0.f, 0.f, 0.f};
    floatx4 O1 = O0, O2 = O0, O3 = O0;

    const int mrow = gq << 6;
    const int psbase = wave * 1152 + m * PITCH;
    const int msw = m & 7;

    for (int kt = 0; kt < 32; ++kt) {
        unsigned short* KT = Kts[kt & 1];
        // ---- stage transposed K tile into dbuf (v_perm packing, swizzled) ----
        const unsigned short* kg = Hb + (((kt << 6) + (p << 1)) << 6) + (cc << 3);
        const half8 ka = *(const half8*)(kg);
        const half8 kb = *(const half8*)(kg + 64);
        union { half8 v; unsigned int u[4]; } kaU, kbU;
        kaU.v = ka;
        kbU.v = kb;
#pragma unroll
        for (int c = 0; c < 4; ++c) {
            const unsigned int ua = kaU.u[c];  // halves d0=8cc+2c (lo16), d0+1 (hi16), j=2p
            const unsigned int ub = kbU.u[c];  // same d's, j=2p+1
            const unsigned int lo = __builtin_amdgcn_perm(ub, ua, 0x05040100);  // row d0
            const unsigned int hi = __builtin_amdgcn_perm(ub, ua, 0x07060302);  // row d0+1
            const int d0 = (cc << 3) + (c << 1);
            const int pos = ((jch ^ cc) << 3) + jo;  // swizzle: 8-way alias -> 2-way
            *(unsigned int*)(&KT[d0 * PITCH + pos]) = lo;
            *(unsigned int*)(&KT[(d0 + 1) * PITCH + pos]) = hi;
        }
        __syncthreads();  // staging visible; dbuf removes the readers-done barrier

        const unsigned int w0 = mbits[mrow + (kt << 1)];
        const unsigned int w1 = mbits[mrow + (kt << 1) + 1];

        // ---- S^T = K * Q^T : A = K rows direct from global (coalesced, L1-hot) ----
        floatx4 a[4];
        const unsigned short* ar = arow + (kt << 12);
#pragma unroll
        for (int jt = 0; jt < 4; ++jt) {
            floatx4 z = {0.f, 0.f, 0.f, 0.f};
            const half8 k0 = *(const half8*)(ar + (jt << 10));
            const half8 k1 = *(const half8*)(ar + (jt << 10) + 32);
            z = __builtin_amdgcn_mfma_f32_16x16x32_f16(k0, bq0, z, 0, 0, 0);
            z = __builtin_amdgcn_mfma_f32_16x16x32_f16(k1, bq1, z, 0, 0, 0);
            a[jt] = z;
        }

        // ---- masked select to sentinel + running max (lane's 16 values all on q-row gq) ----
        float tmx = MRINIT;
#pragma unroll
        for (int jt = 0; jt < 4; ++jt) {
            const unsigned int wv = (jt < 2) ? w0 : w1;
            const unsigned int bits = (wv >> (((jt & 1) << 4) + (quad << 2))) & 0xFu;
#pragma unroll
            for (int reg = 0; reg < 4; ++reg) {
                const float v = ((bits >> reg) & 1u) ? a[jt][reg] : MRINIT;
                a[jt][reg] = v;  // masked -> exp2(MRINIT - mnew) == 0
                tmx = fmaxf(tmx, v);
            }
        }
        tmx = fmaxf(tmx, __shfl_xor(tmx, 16));
        tmx = fmaxf(tmx, __shfl_xor(tmx, 32));
        const float mnew = fmaxf(mr, tmx);
        const float alpha = __builtin_amdgcn_exp2f(mr - mnew);
        const bool need = __any(mnew > mr);

        // ---- p = exp2(s - mnew); pack fp16 pairs; write P (per-wave, swizzled) ----
        float psum = 0.f;
#pragma unroll
        for (int jt = 0; jt < 4; ++jt) {
            const float p0 = __builtin_amdgcn_exp2f(a[jt][0] - mnew);
            const float p1 = __builtin_amdgcn_exp2f(a[jt][1] - mnew);
            const float p2 = __builtin_amdgcn_exp2f(a[jt][2] - mnew);
            const float p3 = __builtin_amdgcn_exp2f(a[jt][3] - mnew);
            psum += (p0 + p1) + (p2 + p3);
            const int ch = (jt << 1) + (quad >> 1);  // j>>3 for j = 16jt+4quad+reg
            *(uint2*)(&Ps[psbase + ((ch ^ msw) << 3) + ((quad & 1) << 2)]) =
                make_uint2(pk2h(p0, p1), pk2h(p2, p3));
        }
        psum += __shfl_xor(psum, 16);
        psum += __shfl_xor(psum, 32);
        lr = lr * alpha + psum;
        mr = mnew;

        // ---- rescale O only when some row's max moved (wave-uniform branch) ----
        if (need) {
            const float aO0 = __shfl(alpha, (quad << 2) + 0);
            const float aO1 = __shfl(alpha, (quad << 2) + 1);
            const float aO2 = __shfl(alpha, (quad << 2) + 2);
            const float aO3 = __shfl(alpha, (quad << 2) + 3);
            O0[0] *= aO0; O0[1] *= aO1; O0[2] *= aO2; O0[3] *= aO3;
            O1[0] *= aO0; O1[1] *= aO1; O1[2] *= aO2; O1[3] *= aO3;
            O2[0] *= aO0; O2[1] *= aO1; O2[2] *= aO2; O2[3] *= aO3;
            O3[0] *= aO0; O3[1] *= aO1; O3[2] *= aO2; O3[3] *= aO3;
        }

        // Ps is per-wave private: same-wave DS ops execute in order; just stop the
        // compiler from reordering the typed stores/loads.
        __builtin_amdgcn_wave_barrier();
        __asm__ __volatile__("" ::: "memory");

        // ---- O += P * V : A = P[m][j] (swizzled), B = V[j][d] from swizzled Kts ----
        const half8 pa0 = *(const half8*)(&Ps[psbase + ((quad ^ msw) << 3)]);
        const half8 pa1 = *(const half8*)(&Ps[psbase + (((4 + quad) ^ msw) << 3)]);
#pragma unroll
        for (int nt = 0; nt < 4; ++nt) {
            const int d = (nt << 4) + m;
            const int sw = (d >> 3) & 7;
            const half8 v0 = *(const half8*)(&KT[d * PITCH + ((quad ^ sw) << 3)]);
            const half8 v1 = *(const half8*)(&KT[d * PITCH + (((4 + quad) ^ sw) << 3)]);
            floatx4& Ont = (nt == 0) ? O0 : (nt == 1) ? O1 : (nt == 2) ? O2 : O3;
            Ont = __builtin_amdgcn_mfma_f32_16x16x32_f16(pa0, v0, Ont, 0, 0, 0);
            Ont = __builtin_amdgcn_mfma_f32_16x16x32_f16(pa1, v1, Ont, 0, 0, 0);
        }
    }

    // ---- epilogue: normalize by l, add bias, leaky; then store fp16 or fused-LN fp32 ----
    const float l0 = 1.f / __shfl(lr, (quad << 2) + 0);
    const float l1 = 1.f / __shfl(lr, (quad << 2) + 1);
    const float l2 = 1.f / __shfl(lr, (quad << 2) + 2);
    const float l3 = 1.f / __shfl(lr, (quad << 2) + 3);
    float g0, g1, g2, g3, be0, be1, be2, be3;
    if (OUTMODE == 1) {
        g0 = gamma[m]; g1 = gamma[16 + m]; g2 = gamma[32 + m]; g3 = gamma[48 + m];
        be0 = beta[m]; be1 = beta[16 + m]; be2 = beta[32 + m]; be3 = beta[48 + m];
    }
    const size_t obase = (((size_t)mat * NN + q0 + (wave << 4) + (quad << 2)) << 6) + m;
#pragma unroll
    for (int reg = 0; reg < 4; ++reg) {
        const float li = (reg == 0) ? l0 : (reg == 1) ? l1 : (reg == 2) ? l2 : l3;
        float z0 = O0[reg] * li + bv0;
        float z1 = O1[reg] * li + bv1;
        float z2 = O2[reg] * li + bv2;
        float z3 = O3[reg] * li + bv3;
        z0 = (z0 > 0.f) ? z0 : 0.2f * z0;  // leaky_relu(0.2) fused for both layers
        z1 = (z1 > 0.f) ? z1 : 0.2f * z1;
        z2 = (z2 > 0.f) ? z2 : 0.2f * z2;
        z3 = (z3 > 0.f) ? z3 : 0.2f * z3;
        if (OUTMODE == 0) {
            unsigned short* op = (unsigned short*)OutP + obase + ((size_t)reg << 6);
            op[0] = f2h(z0); op[16] = f2h(z1); op[32] = f2h(z2); op[48] = f2h(z3);
        } else {
            // fused LayerNorm over the 64 cols of this q-row (16 m-lanes x 4 vals)
            float s = ((z0 + z1) + (z2 + z3));
            float sq = ((z0 * z0 + z1 * z1) + (z2 * z2 + z3 * z3));
#pragma unroll
            for (int off = 1; off < 16; off <<= 1) {
                s += __shfl_xor(s, off);
                sq += __shfl_xor(sq, off);
            }
            const float mu = s * 0.015625f;
            float var = sq * 0.015625f - mu * mu;
            var = fmaxf(var, 0.f);
            const float rstd = rsqrtf(var + 1e-5f);
            float* op = (float*)OutP + obase + ((size_t)reg << 6);
            op[0]  = (z0 - mu) * rstd * g0 + be0;
            op[16] = (z1 - mu) * rstd * g1 + be1;
            op[32] = (z2 - mu) * rstd * g2 + be2;
            op[48] = (z3 - mu) * rstd * g3 + be3;
        }
    }
}

// ---------- h2[b,n,d] = sum_k z[b,n,k] * Wo[d,k];  z = oh (leaky pre-applied), head-major ----------
__global__ __launch_bounds__(256) void mix_kernel(const unsigned short* __restrict__ oh,
                                                  const float* __restrict__ Wo,
                                                  unsigned short* __restrict__ h2) {
    __shared__ float zs[16 * 256];           // 16 KB
    __shared__ unsigned short wsm[64 * 258]; // ~33 KB (fp16 bits)
    const int t = threadIdx.x;
    const int b = blockIdx.x >> 7;
    const int nt = blockIdx.x & 127;
    const int n0 = nt << 4;
    for (int i = t; i < 16384; i += 256) wsm[(i >> 8) * 258 + (i & 255)] = f2h(Wo[i]);
    for (int i = t; i < 4096; i += 256) {
        const int r = i >> 8;
        const int k = i & 255;
        zs[(r << 8) + k] = h2f(oh[((((size_t)b << 2) + (k >> 6)) * NN + n0 + r) * 64 + (k & 63)]);
    }
    __syncthreads();
    const int d = t & 63;
    const int q = t >> 6;
    float a0 = 0.f, a1 = 0.f, a2 = 0.f, a3 = 0.f;
    for (int k = 0; k < 256; ++k) {
        const float w = h2f(wsm[d * 258 + k]);
        a0 += zs[(((q << 2) + 0) << 8) + k] * w;
        a1 += zs[(((q << 2) + 1) << 8) + k] * w;
        a2 += zs[(((q << 2) + 2) << 8) + k] * w;
        a3 += zs[(((q << 2) + 3) << 8) + k] * w;
    }
    unsigned short* hp = h2 + (((size_t)b * NN + n0 + (q << 2)) << 6) + d;
    hp[0]   = f2h(a0);
    hp[64]  = f2h(a1);
    hp[128] = f2h(a2);
    hp[192] = f2h(a3);
}

extern "C" void kernel_launch(void* const* d_in, const int* in_sizes, int n_in,
                              void* d_out, int out_size, void* d_ws, size_t ws_size,
                              hipStream_t stream) {
    const float* x     = (const float*)d_in[0];
    const int*   graph = (const int*)d_in[1];
    const float* Wh    = (const float*)d_in[2];
    const float* bh    = (const float*)d_in[3];
    const float* Wo    = (const float*)d_in[4];
    const float* bo    = (const float*)d_in[5];
    const float* gamma = (const float*)d_in[6];
    const float* beta  = (const float*)d_in[7];
    float* out = (float*)d_out;

    // ---- workspace layout (16.5 MB, with reuse) ----
    char* ws = (char*)d_ws;
    unsigned int* mbits = (unsigned int*)ws;                 // [0, 0.5MB)
    unsigned short* h   = (unsigned short*)(ws + 0x080000);  // fp16 [32,2048,64], dead after gat1
    unsigned short* oh  = (unsigned short*)(ws + 0x880000);  // fp16 [32,2048,64], dead after mix
    unsigned short* h2  = (unsigned short*)(ws + 0x080000);  // overlays h

    mask_kernel<<<16384, 256, 0, stream>>>(graph, mbits);
    proj_kernel<<<4096, 256, 0, stream>>>(x, Wh, h);
    gat_flash<0><<<1024, 256, 0, stream>>>(h, mbits, bh, 4, nullptr, nullptr, oh);   // layer 1
    mix_kernel<<<1024, 256, 0, stream>>>(oh, Wo, h2);
    gat_flash<1><<<256, 256, 0, stream>>>(h2, mbits, bo, 1, gamma, beta, out);       // layer 2 + LN
}

// Round 8
// 266.930 us; speedup vs baseline: 1.2305x; 1.2305x over previous
//
#include <hip/hip_runtime.h>

#define NN 2048
#define PITCH 72  // u16 elems per LDS row: 144B -> 16B-aligned rows

typedef __attribute__((ext_vector_type(8))) _Float16 half8;  // 8 fp16 = 4 VGPRs (MFMA A/B frag)
typedef __attribute__((ext_vector_type(4))) float floatx4;   // MFMA C/D frag

static_assert(sizeof(half8) == 16, "");

#define MRINIT -3.0e38f

__device__ __forceinline__ unsigned short f2h(float f) {
    union { _Float16 h; unsigned short u; } v;
    v.h = (_Float16)f;  // RNE
    return v.u;
}
__device__ __forceinline__ float h2f(unsigned short u) {
    union { unsigned short u; _Float16 h; } v;
    v.u = u;
    return (float)v.h;
}
__device__ __forceinline__ unsigned int pk2h(float a, float b) {  // v_cvt_pkrtz_f16_f32
    union { __fp16 __attribute__((ext_vector_type(2))) h; unsigned int u; } v;
    v.h = __builtin_amdgcn_cvt_pkrtz(a, b);
    return v.u;
}

// ---------- mask = (graph + I) > 0, packed to bits: mbits[i*64 + w] bit b = mask[i][w*32+b] ----------
__global__ __launch_bounds__(256) void mask_kernel(const int* __restrict__ graph,
                                                   unsigned int* __restrict__ mbits) {
    const int t = threadIdx.x;
    const int lane = t & 63;
    const int W = (blockIdx.x << 2) + (t >> 6);  // wave id, 0..65535
    const int i = W >> 5;                        // row 0..2047
    const int cb = W & 31;                       // 64-col chunk
    const int j = (cb << 6) + lane;
    const int g = graph[(size_t)i * NN + j];
    const unsigned long long bal = __ballot((g > 0) || (i == j));
    if (lane == 0)  mbits[(i << 6) + (cb << 1)]     = (unsigned int)bal;
    if (lane == 32) mbits[(i << 6) + (cb << 1) + 1] = (unsigned int)(bal >> 32);
}

// ---------- h[b,h,n,d] = sum_c x[b,n,c] * Wh[h,d,c]  (fp32 in, fp16 out) ----------
__global__ __launch_bounds__(256) void proj_kernel(const float* __restrict__ x,
                                                   const float* __restrict__ Wh,
                                                   unsigned short* __restrict__ hout) {
    __shared__ float xs[16 * 64];   // 4 KB
    __shared__ float wsh[64 * 65];  // 16.25 KB, pad 65 -> conflict-free
    const int t = threadIdx.x;
    const int pair = blockIdx.x >> 7;  // b*4 + hh
    const int nt = blockIdx.x & 127;
    const int n0 = nt << 4;
    const int b = pair >> 2;
    const int hh = pair & 3;
    const float* xb = x + (((size_t)b * NN + n0) << 6);
    for (int i = t; i < 1024; i += 256) xs[i] = xb[i];
    const float* wb = Wh + (hh << 12);
    for (int i = t; i < 4096; i += 256) wsh[(i >> 6) * 65 + (i & 63)] = wb[i];
    __syncthreads();
    const int d = t & 63;
    const int q = t >> 6;
    float a0 = 0.f, a1 = 0.f, a2 = 0.f, a3 = 0.f;
    for (int c = 0; c < 64; ++c) {
        const float w = wsh[d * 65 + c];
        a0 += xs[(((q << 2) + 0) << 6) + c] * w;
        a1 += xs[(((q << 2) + 1) << 6) + c] * w;
        a2 += xs[(((q << 2) + 2) << 6) + c] * w;
        a3 += xs[(((q << 2) + 3) << 6) + c] * w;
    }
    unsigned short* ho = hout + (((size_t)pair * NN + n0 + (q << 2)) << 6) + d;
    ho[0]   = f2h(a0);
    ho[64]  = f2h(a1);
    ho[128] = f2h(a2);
    ho[192] = f2h(a3);
}

// ---------- fused GAT layer: Out[mat,n,:] = softmax_mask(H H^T)[n,:] @ H + bias ----------
// 4 waves/block; QG q-groups of 16 rows per wave (64*QG q-rows/block); K-tiles of 64.
// Flash online softmax in exp2 domain. A-frags (K rows) + V B-frags from LDS, SHARED
// across the QG groups -> LDS cycles per q-row halve at QG=2. Ps is per-wave private
// (same-wave DS ordering; compiler fence only).
// OUTMODE 0: fp16 out, leaky pre-applied (feeds mix). OUTMODE 1: fused leaky+LN, fp32 out.
template <int QG, int OUTMODE>
__global__ __launch_bounds__(256) void gat_flash(const unsigned short* __restrict__ Hm,
                                                 const unsigned int* __restrict__ mbits,
                                                 const float* __restrict__ bias,
                                                 const int bias_mod,
                                                 const float* __restrict__ gamma,
                                                 const float* __restrict__ beta,
                                                 void* __restrict__ OutP) {
    __shared__ unsigned short Ks[64 * PITCH];            // K tile row-major [j][d]
    __shared__ unsigned short Kts[64 * PITCH];           // K tile transposed [d][j], XOR-swizzled
    __shared__ unsigned short Ps[4 * QG * 16 * PITCH];   // per-(wave,group) P [m][j], XOR-swizzled

    const int t = threadIdx.x;
    const int wave = t >> 6;
    const int lane = t & 63;
    const int quad = lane >> 4;
    const int m = lane & 15;

    const int qtbits = (QG == 2) ? 4 : 5;                // qtiles = 16 or 32
    const int mat = blockIdx.x >> qtbits;
    const int qt = blockIdx.x & ((1 << qtbits) - 1);
    const int q0 = qt << ((QG == 2) ? 7 : 6);

    const unsigned short* Hb = Hm + ((size_t)mat << 17);  // mat * 2048 * 64
    const int wbase = q0 + wave * (16 * QG);

    // Q B-frags per group, loaded once; scaled by log2(e) -> exp2 domain (exact)
    const _Float16 LOG2E = (_Float16)1.44269504f;
    half8 bq0[QG], bq1[QG];
    int gq[QG];
#pragma unroll
    for (int g = 0; g < QG; ++g) {
        gq[g] = wbase + (g << 4) + m;
        bq0[g] = *(const half8*)(Hb + (gq[g] << 6) + (quad << 3)) * LOG2E;
        bq1[g] = *(const half8*)(Hb + (gq[g] << 6) + 32 + (quad << 3)) * LOG2E;
    }

    const int boff = (mat % bias_mod) << 6;
    const float bv0 = bias[boff + m];
    const float bv1 = bias[boff + 16 + m];
    const float bv2 = bias[boff + 32 + m];
    const float bv3 = bias[boff + 48 + m];

    // staging assignment: thread -> rows {2p, 2p+1}, d-chunk cc
    const int p = t >> 3;
    const int cc = t & 7;
    const int jch = p >> 2;         // j-chunk for transposed writes
    const int jo = (p & 3) << 1;    // u16 offset within 8-elem chunk

    float mr[QG], lr[QG];
    floatx4 O[QG][4];
#pragma unroll
    for (int g = 0; g < QG; ++g) {
        mr[g] = MRINIT;
        lr[g] = 0.f;
#pragma unroll
        for (int nt = 0; nt < 4; ++nt) O[g][nt] = floatx4{0.f, 0.f, 0.f, 0.f};
    }

    const int msw = m & 7;
    int psb[QG];
#pragma unroll
    for (int g = 0; g < QG; ++g) psb[g] = (wave * QG + g) * 1152 + m * PITCH;

    for (int kt = 0; kt < 32; ++kt) {
        __syncthreads();  // previous tile's readers done before restaging
        // ---- stage K tile: row-major Ks + swizzled transposed Kts (v_perm packing) ----
        const unsigned short* kg = Hb + (((kt << 6) + (p << 1)) << 6) + (cc << 3);
        const half8 ka = *(const half8*)(kg);
        const half8 kb = *(const half8*)(kg + 64);
        *(half8*)(&Ks[(p << 1) * PITCH + (cc << 3)]) = ka;
        *(half8*)(&Ks[((p << 1) + 1) * PITCH + (cc << 3)]) = kb;
        union { half8 v; unsigned int u[4]; } kaU, kbU;
        kaU.v = ka;
        kbU.v = kb;
#pragma unroll
        for (int c = 0; c < 4; ++c) {
            const unsigned int ua = kaU.u[c];  // halves d0=8cc+2c (lo16), d0+1 (hi16), j=2p
            const unsigned int ub = kbU.u[c];  // same d's, j=2p+1
            const unsigned int lo = __builtin_amdgcn_perm(ub, ua, 0x05040100);  // row d0
            const unsigned int hi = __builtin_amdgcn_perm(ub, ua, 0x07060302);  // row d0+1
            const int d0 = (cc << 3) + (c << 1);
            const int pos = ((jch ^ cc) << 3) + jo;  // swizzle: 8-way alias -> 2-way
            *(unsigned int*)(&Kts[d0 * PITCH + pos]) = lo;
            *(unsigned int*)(&Kts[(d0 + 1) * PITCH + pos]) = hi;
        }
        __syncthreads();

        // ---- S^T = K * Q^T : A = K[16jt+m][d] from LDS, B = Q[g] (regs); A shared over groups ----
        floatx4 a[QG][4];
#pragma unroll
        for (int jt = 0; jt < 4; ++jt) {
            const half8 k0 = *(const half8*)(&Ks[((jt << 4) + m) * PITCH + (quad << 3)]);
            const half8 k1 = *(const half8*)(&Ks[((jt << 4) + m) * PITCH + 32 + (quad << 3)]);
#pragma unroll
            for (int g = 0; g < QG; ++g) {
                floatx4 z = {0.f, 0.f, 0.f, 0.f};
                z = __builtin_amdgcn_mfma_f32_16x16x32_f16(k0, bq0[g], z, 0, 0, 0);
                z = __builtin_amdgcn_mfma_f32_16x16x32_f16(k1, bq1[g], z, 0, 0, 0);
                a[g][jt] = z;
            }
        }

        // ---- per group: mask, online softmax, Ps write, O rescale ----
#pragma unroll
        for (int g = 0; g < QG; ++g) {
            const int mrow = gq[g] << 6;
            const unsigned int w0 = mbits[mrow + (kt << 1)];
            const unsigned int w1 = mbits[mrow + (kt << 1) + 1];

            float tmx = MRINIT;
#pragma unroll
            for (int jt = 0; jt < 4; ++jt) {
                const unsigned int wv = (jt < 2) ? w0 : w1;
                const unsigned int bits = (wv >> (((jt & 1) << 4) + (quad << 2))) & 0xFu;
#pragma unroll
                for (int reg = 0; reg < 4; ++reg) {
                    const float v = ((bits >> reg) & 1u) ? a[g][jt][reg] : MRINIT;
                    a[g][jt][reg] = v;  // masked -> exp2(MRINIT - mnew) == 0
                    tmx = fmaxf(tmx, v);
                }
            }
            tmx = fmaxf(tmx, __shfl_xor(tmx, 16));
            tmx = fmaxf(tmx, __shfl_xor(tmx, 32));
            const float mnew = fmaxf(mr[g], tmx);
            const float alpha = __builtin_amdgcn_exp2f(mr[g] - mnew);
            const bool need = __any(mnew > mr[g]);

            float psum = 0.f;
#pragma unroll
            for (int jt = 0; jt < 4; ++jt) {
                const float p0 = __builtin_amdgcn_exp2f(a[g][jt][0] - mnew);
                const float p1 = __builtin_amdgcn_exp2f(a[g][jt][1] - mnew);
                const float p2 = __builtin_amdgcn_exp2f(a[g][jt][2] - mnew);
                const float p3 = __builtin_amdgcn_exp2f(a[g][jt][3] - mnew);
                psum += (p0 + p1) + (p2 + p3);
                const int ch = (jt << 1) + (quad >> 1);  // j>>3 for j = 16jt+4quad+reg
                *(uint2*)(&Ps[psb[g] + ((ch ^ msw) << 3) + ((quad & 1) << 2)]) =
                    make_uint2(pk2h(p0, p1), pk2h(p2, p3));
            }
            psum += __shfl_xor(psum, 16);
            psum += __shfl_xor(psum, 32);
            lr[g] = lr[g] * alpha + psum;
            mr[g] = mnew;

            if (need) {
                const float aO0 = __shfl(alpha, (quad << 2) + 0);
                const float aO1 = __shfl(alpha, (quad << 2) + 1);
                const float aO2 = __shfl(alpha, (quad << 2) + 2);
                const float aO3 = __shfl(alpha, (quad << 2) + 3);
#pragma unroll
                for (int nt = 0; nt < 4; ++nt) {
                    O[g][nt][0] *= aO0;
                    O[g][nt][1] *= aO1;
                    O[g][nt][2] *= aO2;
                    O[g][nt][3] *= aO3;
                }
            }
        }

        // Ps is per-wave private: same-wave DS ops are ordered; stop compiler reordering only.
        __builtin_amdgcn_wave_barrier();
        __asm__ __volatile__("" ::: "memory");

        // ---- O += P * V : A = P[g] (swizzled), B = V[j][d] from swizzled Kts (shared) ----
        half8 pa0[QG], pa1[QG];
#pragma unroll
        for (int g = 0; g < QG; ++g) {
            pa0[g] = *(const half8*)(&Ps[psb[g] + ((quad ^ msw) << 3)]);
            pa1[g] = *(const half8*)(&Ps[psb[g] + (((4 + quad) ^ msw) << 3)]);
        }
#pragma unroll
        for (int nt = 0; nt < 4; ++nt) {
            const int d = (nt << 4) + m;
            const int sw = (d >> 3) & 7;
            const half8 v0 = *(const half8*)(&Kts[d * PITCH + ((quad ^ sw) << 3)]);
            const half8 v1 = *(const half8*)(&Kts[d * PITCH + (((4 + quad) ^ sw) << 3)]);
#pragma unroll
            for (int g = 0; g < QG; ++g) {
                O[g][nt] = __builtin_amdgcn_mfma_f32_16x16x32_f16(pa0[g], v0, O[g][nt], 0, 0, 0);
                O[g][nt] = __builtin_amdgcn_mfma_f32_16x16x32_f16(pa1[g], v1, O[g][nt], 0, 0, 0);
            }
        }
    }

    // ---- epilogue per group: 1/l, +bias, leaky; fp16 store or fused LayerNorm fp32 ----
    float g0, g1, g2, g3, be0, be1, be2, be3;
    if (OUTMODE == 1) {
        g0 = gamma[m]; g1 = gamma[16 + m]; g2 = gamma[32 + m]; g3 = gamma[48 + m];
        be0 = beta[m]; be1 = beta[16 + m]; be2 = beta[32 + m]; be3 = beta[48 + m];
    }
#pragma unroll
    for (int g = 0; g < QG; ++g) {
        const float l0 = 1.f / __shfl(lr[g], (quad << 2) + 0);
        const float l1 = 1.f / __shfl(lr[g], (quad << 2) + 1);
        const float l2 = 1.f / __shfl(lr[g], (quad << 2) + 2);
        const float l3 = 1.f / __shfl(lr[g], (quad << 2) + 3);
        const size_t obase = (((size_t)mat * NN + wbase + (g << 4) + (quad << 2)) << 6) + m;
#pragma unroll
        for (int reg = 0; reg < 4; ++reg) {
            const float li = (reg == 0) ? l0 : (reg == 1) ? l1 : (reg == 2) ? l2 : l3;
            float z0 = O[g][0][reg] * li + bv0;
            float z1 = O[g][1][reg] * li + bv1;
            float z2 = O[g][2][reg] * li + bv2;
            float z3 = O[g][3][reg] * li + bv3;
            z0 = (z0 > 0.f) ? z0 : 0.2f * z0;  // leaky_relu(0.2), both layers
            z1 = (z1 > 0.f) ? z1 : 0.2f * z1;
            z2 = (z2 > 0.f) ? z2 : 0.2f * z2;
            z3 = (z3 > 0.f) ? z3 : 0.2f * z3;
            if (OUTMODE == 0) {
                unsigned short* op = (unsigned short*)OutP + obase + ((size_t)reg << 6);
                op[0] = f2h(z0); op[16] = f2h(z1); op[32] = f2h(z2); op[48] = f2h(z3);
            } else {
                float s = ((z0 + z1) + (z2 + z3));
                float sq = ((z0 * z0 + z1 * z1) + (z2 * z2 + z3 * z3));
#pragma unroll
                for (int off = 1; off < 16; off <<= 1) {
                    s += __shfl_xor(s, off);
                    sq += __shfl_xor(sq, off);
                }
                const float mu = s * 0.015625f;
                float var = sq * 0.015625f - mu * mu;
                var = fmaxf(var, 0.f);
                const float rstd = rsqrtf(var + 1e-5f);
                float* op = (float*)OutP + obase + ((size_t)reg << 6);
                op[0]  = (z0 - mu) * rstd * g0 + be0;
                op[16] = (z1 - mu) * rstd * g1 + be1;
                op[32] = (z2 - mu) * rstd * g2 + be2;
                op[48] = (z3 - mu) * rstd * g3 + be3;
            }
        }
    }
}

// ---------- h2[b,n,d] = sum_k z[b,n,k] * Wo[d,k];  z = oh (leaky pre-applied), head-major ----------
__global__ __launch_bounds__(256) void mix_kernel(const unsigned short* __restrict__ oh,
                                                  const float* __restrict__ Wo,
                                                  unsigned short* __restrict__ h2) {
    __shared__ float zs[16 * 256];           // 16 KB
    __shared__ unsigned short wsm[64 * 258]; // ~33 KB (fp16 bits)
    const int t = threadIdx.x;
    const int b = blockIdx.x >> 7;
    const int nt = blockIdx.x & 127;
    const int n0 = nt << 4;
    for (int i = t; i < 16384; i += 256) wsm[(i >> 8) * 258 + (i & 255)] = f2h(Wo[i]);
    for (int i = t; i < 4096; i += 256) {
        const int r = i >> 8;
        const int k = i & 255;
        zs[(r << 8) + k] = h2f(oh[((((size_t)b << 2) + (k >> 6)) * NN + n0 + r) * 64 + (k & 63)]);
    }
    __syncthreads();
    const int d = t & 63;
    const int q = t >> 6;
    float a0 = 0.f, a1 = 0.f, a2 = 0.f, a3 = 0.f;
    for (int k = 0; k < 256; ++k) {
        const float w = h2f(wsm[d * 258 + k]);
        a0 += zs[(((q << 2) + 0) << 8) + k] * w;
        a1 += zs[(((q << 2) + 1) << 8) + k] * w;
        a2 += zs[(((q << 2) + 2) << 8) + k] * w;
        a3 += zs[(((q << 2) + 3) << 8) + k] * w;
    }
    unsigned short* hp = h2 + (((size_t)b * NN + n0 + (q << 2)) << 6) + d;
    hp[0]   = f2h(a0);
    hp[64]  = f2h(a1);
    hp[128] = f2h(a2);
    hp[192] = f2h(a3);
}

extern "C" void kernel_launch(void* const* d_in, const int* in_sizes, int n_in,
                              void* d_out, int out_size, void* d_ws, size_t ws_size,
                              hipStream_t stream) {
    const float* x     = (const float*)d_in[0];
    const int*   graph = (const int*)d_in[1];
    const float* Wh    = (const float*)d_in[2];
    const float* bh    = (const float*)d_in[3];
    const float* Wo    = (const float*)d_in[4];
    const float* bo    = (const float*)d_in[5];
    const float* gamma = (const float*)d_in[6];
    const float* beta  = (const float*)d_in[7];
    float* out = (float*)d_out;

    // ---- workspace layout (16.5 MB, with reuse) ----
    char* ws = (char*)d_ws;
    unsigned int* mbits = (unsigned int*)ws;                 // [0, 0.5MB)
    unsigned short* h   = (unsigned short*)(ws + 0x080000);  // fp16 [32,2048,64], dead after gat1
    unsigned short* oh  = (unsigned short*)(ws + 0x880000);  // fp16 [32,2048,64], dead after mix
    unsigned short* h2  = (unsigned short*)(ws + 0x080000);  // overlays h

    mask_kernel<<<16384, 256, 0, stream>>>(graph, mbits);
    proj_kernel<<<4096, 256, 0, stream>>>(x, Wh, h);
    gat_flash<2, 0><<<512, 256, 0, stream>>>(h, mbits, bh, 4, nullptr, nullptr, oh);   // layer 1
    mix_kernel<<<1024, 256, 0, stream>>>(oh, Wo, h2);
    gat_flash<1, 1><<<256, 256, 0, stream>>>(h2, mbits, bo, 1, gamma, beta, out);      // layer 2 + LN
}

// Round 9
// 253.646 us; speedup vs baseline: 1.2949x; 1.0524x over previous
//
#include <hip/hip_runtime.h>

#define NN 2048
#define PITCH 72  // u16 elems per LDS row: 144B -> 16B-aligned rows

typedef __attribute__((ext_vector_type(8))) _Float16 half8;  // 8 fp16 = 4 VGPRs (MFMA A/B frag)
typedef __attribute__((ext_vector_type(4))) float floatx4;   // MFMA C/D frag

static_assert(sizeof(half8) == 16, "");

#define MRINIT -3.0e38f

__device__ __forceinline__ unsigned short f2h(float f) {
    union { _Float16 h; unsigned short u; } v;
    v.h = (_Float16)f;  // RNE
    return v.u;
}
__device__ __forceinline__ float h2f(unsigned short u) {
    union { unsigned short u; _Float16 h; } v;
    v.u = u;
    return (float)v.h;
}
__device__ __forceinline__ unsigned int pk2h(float a, float b) {  // v_cvt_pkrtz_f16_f32
    union { __fp16 __attribute__((ext_vector_type(2))) h; unsigned int u; } v;
    v.h = __builtin_amdgcn_cvt_pkrtz(a, b);
    return v.u;
}
// barrier that does NOT drain vmcnt: LDS-visibility only (lgkmcnt(0)), prefetch
// global loads stay in flight across it (hipBLASLt-style).
__device__ __forceinline__ void barrier_lds_only() {
    __asm__ __volatile__("" ::: "memory");
    __builtin_amdgcn_s_waitcnt(0xC07F);  // vmcnt=63, expcnt=7, lgkmcnt=0
    __builtin_amdgcn_s_barrier();
    __asm__ __volatile__("" ::: "memory");
}

// ---------- mask = (graph + I) > 0, packed to bits: mbits[i*64 + w] bit b = mask[i][w*32+b] ----------
__global__ __launch_bounds__(256) void mask_kernel(const int* __restrict__ graph,
                                                   unsigned int* __restrict__ mbits) {
    const int t = threadIdx.x;
    const int lane = t & 63;
    const int W = (blockIdx.x << 2) + (t >> 6);  // wave id, 0..65535
    const int i = W >> 5;                        // row 0..2047
    const int cb = W & 31;                       // 64-col chunk
    const int j = (cb << 6) + lane;
    const int g = graph[(size_t)i * NN + j];
    const unsigned long long bal = __ballot((g > 0) || (i == j));
    if (lane == 0)  mbits[(i << 6) + (cb << 1)]     = (unsigned int)bal;
    if (lane == 32) mbits[(i << 6) + (cb << 1) + 1] = (unsigned int)(bal >> 32);
}

// ---------- h[b,h,n,d] = sum_c x[b,n,c] * Wh[h,d,c]  (fp32 in, fp16 out) ----------
__global__ __launch_bounds__(256) void proj_kernel(const float* __restrict__ x,
                                                   const float* __restrict__ Wh,
                                                   unsigned short* __restrict__ hout) {
    __shared__ float xs[16 * 64];   // 4 KB
    __shared__ float wsh[64 * 65];  // 16.25 KB, pad 65 -> conflict-free
    const int t = threadIdx.x;
    const int pair = blockIdx.x >> 7;  // b*4 + hh
    const int nt = blockIdx.x & 127;
    const int n0 = nt << 4;
    const int b = pair >> 2;
    const int hh = pair & 3;
    const float* xb = x + (((size_t)b * NN + n0) << 6);
    for (int i = t; i < 1024; i += 256) xs[i] = xb[i];
    const float* wb = Wh + (hh << 12);
    for (int i = t; i < 4096; i += 256) wsh[(i >> 6) * 65 + (i & 63)] = wb[i];
    __syncthreads();
    const int d = t & 63;
    const int q = t >> 6;
    float a0 = 0.f, a1 = 0.f, a2 = 0.f, a3 = 0.f;
    for (int c = 0; c < 64; ++c) {
        const float w = wsh[d * 65 + c];
        a0 += xs[(((q << 2) + 0) << 6) + c] * w;
        a1 += xs[(((q << 2) + 1) << 6) + c] * w;
        a2 += xs[(((q << 2) + 2) << 6) + c] * w;
        a3 += xs[(((q << 2) + 3) << 6) + c] * w;
    }
    unsigned short* ho = hout + (((size_t)pair * NN + n0 + (q << 2)) << 6) + d;
    ho[0]   = f2h(a0);
    ho[64]  = f2h(a1);
    ho[128] = f2h(a2);
    ho[192] = f2h(a3);
}

// ---------- fused GAT layer: Out[mat,n,:] = softmax_mask(H H^T)[n,:] @ H + bias ----------
// 4 waves/block; QG q-groups of 16 rows/wave; K-tiles of 64; flash softmax (exp2 domain).
// Software pipeline: K-tile kt+1 global->VGPR prefetch issued during compute of kt;
// Ks/Kts double-buffered; ONE lgkm-only barrier per iter (vmcnt stays in flight).
// OUTMODE 0: fp16 out, leaky pre-applied. OUTMODE 1: fused leaky+LayerNorm, fp32 out.
template <int QG, int OUTMODE>
__global__ __launch_bounds__(256) void gat_flash(const unsigned short* __restrict__ Hm,
                                                 const unsigned int* __restrict__ mbits,
                                                 const float* __restrict__ bias,
                                                 const int bias_mod,
                                                 const float* __restrict__ gamma,
                                                 const float* __restrict__ beta,
                                                 void* __restrict__ OutP) {
    __shared__ unsigned short Ks[2][64 * PITCH];         // K tile row-major [j][d], dbuf
    __shared__ unsigned short Kts[2][64 * PITCH];        // K tile transposed [d][j], swizzled, dbuf
    __shared__ unsigned short Ps[4 * QG * 16 * PITCH];   // per-(wave,group) P [m][j], swizzled

    const int t = threadIdx.x;
    const int wave = t >> 6;
    const int lane = t & 63;
    const int quad = lane >> 4;
    const int m = lane & 15;

    const int qtbits = (QG == 2) ? 4 : 5;                // qtiles = 16 or 32
    const int mat = blockIdx.x >> qtbits;
    const int qt = blockIdx.x & ((1 << qtbits) - 1);
    const int q0 = qt << ((QG == 2) ? 7 : 6);

    const unsigned short* Hb = Hm + ((size_t)mat << 17);  // mat * 2048 * 64
    const int wbase = q0 + wave * (16 * QG);

    // Q B-frags per group, loaded once; scaled by log2(e) -> exp2 domain (exact)
    const _Float16 LOG2E = (_Float16)1.44269504f;
    half8 bq0[QG], bq1[QG];
    int gq[QG];
#pragma unroll
    for (int g = 0; g < QG; ++g) {
        gq[g] = wbase + (g << 4) + m;
        bq0[g] = *(const half8*)(Hb + (gq[g] << 6) + (quad << 3)) * LOG2E;
        bq1[g] = *(const half8*)(Hb + (gq[g] << 6) + 32 + (quad << 3)) * LOG2E;
    }

    const int boff = (mat % bias_mod) << 6;
    const float bv0 = bias[boff + m];
    const float bv1 = bias[boff + 16 + m];
    const float bv2 = bias[boff + 32 + m];
    const float bv3 = bias[boff + 48 + m];

    // staging assignment: thread -> rows {2p, 2p+1}, d-chunk cc
    const int p = t >> 3;
    const int cc = t & 7;
    const int jch = p >> 2;         // j-chunk for transposed writes
    const int jo = (p & 3) << 1;    // u16 offset within 8-elem chunk

    float mr[QG], lr[QG];
    floatx4 O[QG][4];
#pragma unroll
    for (int g = 0; g < QG; ++g) {
        mr[g] = MRINIT;
        lr[g] = 0.f;
#pragma unroll
        for (int nt = 0; nt < 4; ++nt) O[g][nt] = floatx4{0.f, 0.f, 0.f, 0.f};
    }

    const int msw = m & 7;
    int psb[QG];
#pragma unroll
    for (int g = 0; g < QG; ++g) psb[g] = (wave * QG + g) * 1152 + m * PITCH;

    // ---- prefetch tile 0 into registers ----
    const unsigned short* kg0 = Hb + ((p << 1) << 6) + (cc << 3);
    half8 ra = *(const half8*)(kg0);
    half8 rb = *(const half8*)(kg0 + 64);

    for (int kt = 0; kt < 32; ++kt) {
        unsigned short* KS = Ks[kt & 1];
        unsigned short* KT = Kts[kt & 1];
        // ---- write prefetched tile kt (VGPR->LDS); vmcnt wait lands HERE, one iter late ----
        *(half8*)(&KS[(p << 1) * PITCH + (cc << 3)]) = ra;
        *(half8*)(&KS[((p << 1) + 1) * PITCH + (cc << 3)]) = rb;
        union { half8 v; unsigned int u[4]; } kaU, kbU;
        kaU.v = ra;
        kbU.v = rb;
#pragma unroll
        for (int c = 0; c < 4; ++c) {
            const unsigned int ua = kaU.u[c];  // halves d0=8cc+2c (lo16), d0+1 (hi16), j=2p
            const unsigned int ub = kbU.u[c];  // same d's, j=2p+1
            const unsigned int lo = __builtin_amdgcn_perm(ub, ua, 0x05040100);  // row d0
            const unsigned int hi = __builtin_amdgcn_perm(ub, ua, 0x07060302);  // row d0+1
            const int d0 = (cc << 3) + (c << 1);
            const int pos = ((jch ^ cc) << 3) + jo;  // swizzle: 8-way alias -> 2-way
            *(unsigned int*)(&KT[d0 * PITCH + pos]) = lo;
            *(unsigned int*)(&KT[(d0 + 1) * PITCH + pos]) = hi;
        }
        // ---- issue prefetch for tile kt+1 (wraps to 0; stays in flight across barrier) ----
        const int ktn = (kt + 1) & 31;
        const unsigned short* kgn = Hb + (((ktn << 6) + (p << 1)) << 6) + (cc << 3);
        ra = *(const half8*)(kgn);
        rb = *(const half8*)(kgn + 64);

        barrier_lds_only();  // staging visible; dbuf => no readers-done barrier needed

        // ---- S^T = K * Q^T : A = K[16jt+m][d] from LDS, shared across groups ----
        floatx4 a[QG][4];
#pragma unroll
        for (int jt = 0; jt < 4; ++jt) {
            const half8 k0 = *(const half8*)(&KS[((jt << 4) + m) * PITCH + (quad << 3)]);
            const half8 k1 = *(const half8*)(&KS[((jt << 4) + m) * PITCH + 32 + (quad << 3)]);
#pragma unroll
            for (int g = 0; g < QG; ++g) {
                floatx4 z = {0.f, 0.f, 0.f, 0.f};
                z = __builtin_amdgcn_mfma_f32_16x16x32_f16(k0, bq0[g], z, 0, 0, 0);
                z = __builtin_amdgcn_mfma_f32_16x16x32_f16(k1, bq1[g], z, 0, 0, 0);
                a[g][jt] = z;
            }
        }

        // ---- per group: mask, online softmax, Ps write, O rescale ----
#pragma unroll
        for (int g = 0; g < QG; ++g) {
            const int mrow = gq[g] << 6;
            const unsigned int w0 = mbits[mrow + (kt << 1)];
            const unsigned int w1 = mbits[mrow + (kt << 1) + 1];

            float tmx = MRINIT;
#pragma unroll
            for (int jt = 0; jt < 4; ++jt) {
                const unsigned int wv = (jt < 2) ? w0 : w1;
                const unsigned int bits = (wv >> (((jt & 1) << 4) + (quad << 2))) & 0xFu;
#pragma unroll
                for (int reg = 0; reg < 4; ++reg) {
                    const float v = ((bits >> reg) & 1u) ? a[g][jt][reg] : MRINIT;
                    a[g][jt][reg] = v;  // masked -> exp2(MRINIT - mnew) == 0
                    tmx = fmaxf(tmx, v);
                }
            }
            tmx = fmaxf(tmx, __shfl_xor(tmx, 16));
            tmx = fmaxf(tmx, __shfl_xor(tmx, 32));
            const float mnew = fmaxf(mr[g], tmx);
            const float alpha = __builtin_amdgcn_exp2f(mr[g] - mnew);
            const bool need = __any(mnew > mr[g]);

            float psum = 0.f;
#pragma unroll
            for (int jt = 0; jt < 4; ++jt) {
                const float p0 = __builtin_amdgcn_exp2f(a[g][jt][0] - mnew);
                const float p1 = __builtin_amdgcn_exp2f(a[g][jt][1] - mnew);
                const float p2 = __builtin_amdgcn_exp2f(a[g][jt][2] - mnew);
                const float p3 = __builtin_amdgcn_exp2f(a[g][jt][3] - mnew);
                psum += (p0 + p1) + (p2 + p3);
                const int ch = (jt << 1) + (quad >> 1);  // j>>3 for j = 16jt+4quad+reg
                *(uint2*)(&Ps[psb[g] + ((ch ^ msw) << 3) + ((quad & 1) << 2)]) =
                    make_uint2(pk2h(p0, p1), pk2h(p2, p3));
            }
            psum += __shfl_xor(psum, 16);
            psum += __shfl_xor(psum, 32);
            lr[g] = lr[g] * alpha + psum;
            mr[g] = mnew;

            if (need) {
                const float aO0 = __shfl(alpha, (quad << 2) + 0);
                const float aO1 = __shfl(alpha, (quad << 2) + 1);
                const float aO2 = __shfl(alpha, (quad << 2) + 2);
                const float aO3 = __shfl(alpha, (quad << 2) + 3);
#pragma unroll
                for (int nt = 0; nt < 4; ++nt) {
                    O[g][nt][0] *= aO0;
                    O[g][nt][1] *= aO1;
                    O[g][nt][2] *= aO2;
                    O[g][nt][3] *= aO3;
                }
            }
        }

        // Ps is per-wave private: same-wave DS ops are ordered; block compiler reordering only.
        __builtin_amdgcn_wave_barrier();
        __asm__ __volatile__("" ::: "memory");

        // ---- O += P * V : A = P[g] (swizzled), B = V[j][d] from swizzled Kts (shared) ----
        half8 pa0[QG], pa1[QG];
#pragma unroll
        for (int g = 0; g < QG; ++g) {
            pa0[g] = *(const half8*)(&Ps[psb[g] + ((quad ^ msw) << 3)]);
            pa1[g] = *(const half8*)(&Ps[psb[g] + (((4 + quad) ^ msw) << 3)]);
        }
#pragma unroll
        for (int nt = 0; nt < 4; ++nt) {
            const int d = (nt << 4) + m;
            const int sw = (d >> 3) & 7;
            const half8 v0 = *(const half8*)(&KT[d * PITCH + ((quad ^ sw) << 3)]);
            const half8 v1 = *(const half8*)(&KT[d * PITCH + (((4 + quad) ^ sw) << 3)]);
#pragma unroll
            for (int g = 0; g < QG; ++g) {
                O[g][nt] = __builtin_amdgcn_mfma_f32_16x16x32_f16(pa0[g], v0, O[g][nt], 0, 0, 0);
                O[g][nt] = __builtin_amdgcn_mfma_f32_16x16x32_f16(pa1[g], v1, O[g][nt], 0, 0, 0);
            }
        }
    }

    // ---- epilogue per group: 1/l, +bias, leaky; fp16 store or fused LayerNorm fp32 ----
    float g0, g1, g2, g3, be0, be1, be2, be3;
    if (OUTMODE == 1) {
        g0 = gamma[m]; g1 = gamma[16 + m]; g2 = gamma[32 + m]; g3 = gamma[48 + m];
        be0 = beta[m]; be1 = beta[16 + m]; be2 = beta[32 + m]; be3 = beta[48 + m];
    }
#pragma unroll
    for (int g = 0; g < QG; ++g) {
        const float l0 = 1.f / __shfl(lr[g], (quad << 2) + 0);
        const float l1 = 1.f / __shfl(lr[g], (quad << 2) + 1);
        const float l2 = 1.f / __shfl(lr[g], (quad << 2) + 2);
        const float l3 = 1.f / __shfl(lr[g], (quad << 2) + 3);
        const size_t obase = (((size_t)mat * NN + wbase + (g << 4) + (quad << 2)) << 6) + m;
#pragma unroll
        for (int reg = 0; reg < 4; ++reg) {
            const float li = (reg == 0) ? l0 : (reg == 1) ? l1 : (reg == 2) ? l2 : l3;
            float z0 = O[g][0][reg] * li + bv0;
            float z1 = O[g][1][reg] * li + bv1;
            float z2 = O[g][2][reg] * li + bv2;
            float z3 = O[g][3][reg] * li + bv3;
            z0 = (z0 > 0.f) ? z0 : 0.2f * z0;  // leaky_relu(0.2), both layers
            z1 = (z1 > 0.f) ? z1 : 0.2f * z1;
            z2 = (z2 > 0.f) ? z2 : 0.2f * z2;
            z3 = (z3 > 0.f) ? z3 : 0.2f * z3;
            if (OUTMODE == 0) {
                unsigned short* op = (unsigned short*)OutP + obase + ((size_t)reg << 6);
                op[0] = f2h(z0); op[16] = f2h(z1); op[32] = f2h(z2); op[48] = f2h(z3);
            } else {
                float s = ((z0 + z1) + (z2 + z3));
                float sq = ((z0 * z0 + z1 * z1) + (z2 * z2 + z3 * z3));
#pragma unroll
                for (int off = 1; off < 16; off <<= 1) {
                    s += __shfl_xor(s, off);
                    sq += __shfl_xor(sq, off);
                }
                const float mu = s * 0.015625f;
                float var = sq * 0.015625f - mu * mu;
                var = fmaxf(var, 0.f);
                const float rstd = rsqrtf(var + 1e-5f);
                float* op = (float*)OutP + obase + ((size_t)reg << 6);
                op[0]  = (z0 - mu) * rstd * g0 + be0;
                op[16] = (z1 - mu) * rstd * g1 + be1;
                op[32] = (z2 - mu) * rstd * g2 + be2;
                op[48] = (z3 - mu) * rstd * g3 + be3;
            }
        }
    }
}

// ---------- h2[b,n,d] = sum_k z[b,n,k] * Wo[d,k];  z = oh (leaky pre-applied), head-major ----------
__global__ __launch_bounds__(256) void mix_kernel(const unsigned short* __restrict__ oh,
                                                  const float* __restrict__ Wo,
                                                  unsigned short* __restrict__ h2) {
    __shared__ float zs[16 * 256];           // 16 KB
    __shared__ unsigned short wsm[64 * 258]; // ~33 KB (fp16 bits)
    const int t = threadIdx.x;
    const int b = blockIdx.x >> 7;
    const int nt = blockIdx.x & 127;
    const int n0 = nt << 4;
    for (int i = t; i < 16384; i += 256) wsm[(i >> 8) * 258 + (i & 255)] = f2h(Wo[i]);
    for (int i = t; i < 4096; i += 256) {
        const int r = i >> 8;
        const int k = i & 255;
        zs[(r << 8) + k] = h2f(oh[((((size_t)b << 2) + (k >> 6)) * NN + n0 + r) * 64 + (k & 63)]);
    }
    __syncthreads();
    const int d = t & 63;
    const int q = t >> 6;
    float a0 = 0.f, a1 = 0.f, a2 = 0.f, a3 = 0.f;
    for (int k = 0; k < 256; ++k) {
        const float w = h2f(wsm[d * 258 + k]);
        a0 += zs[(((q << 2) + 0) << 8) + k] * w;
        a1 += zs[(((q << 2) + 1) << 8) + k] * w;
        a2 += zs[(((q << 2) + 2) << 8) + k] * w;
        a3 += zs[(((q << 2) + 3) << 8) + k] * w;
    }
    unsigned short* hp = h2 + (((size_t)b * NN + n0 + (q << 2)) << 6) + d;
    hp[0]   = f2h(a0);
    hp[64]  = f2h(a1);
    hp[128] = f2h(a2);
    hp[192] = f2h(a3);
}

extern "C" void kernel_launch(void* const* d_in, const int* in_sizes, int n_in,
                              void* d_out, int out_size, void* d_ws, size_t ws_size,
                              hipStream_t stream) {
    const float* x     = (const float*)d_in[0];
    const int*   graph = (const int*)d_in[1];
    const float* Wh    = (const float*)d_in[2];
    const float* bh    = (const float*)d_in[3];
    const float* Wo    = (const float*)d_in[4];
    const float* bo    = (const float*)d_in[5];
    const float* gamma = (const float*)d_in[6];
    const float* beta  = (const float*)d_in[7];
    float* out = (float*)d_out;

    // ---- workspace layout (16.5 MB, with reuse) ----
    char* ws = (char*)d_ws;
    unsigned int* mbits = (unsigned int*)ws;                 // [0, 0.5MB)
    unsigned short* h   = (unsigned short*)(ws + 0x080000);  // fp16 [32,2048,64], dead after gat1
    unsigned short* oh  = (unsigned short*)(ws + 0x880000);  // fp16 [32,2048,64], dead after mix
    unsigned short* h2  = (unsigned short*)(ws + 0x080000);  // overlays h

    mask_kernel<<<16384, 256, 0, stream>>>(graph, mbits);
    proj_kernel<<<4096, 256, 0, stream>>>(x, Wh, h);
    gat_flash<2, 0><<<512, 256, 0, stream>>>(h, mbits, bh, 4, nullptr, nullptr, oh);   // layer 1
    mix_kernel<<<1024, 256, 0, stream>>>(oh, Wo, h2);
    gat_flash<1, 1><<<256, 256, 0, stream>>>(h2, mbits, bo, 1, gamma, beta, out);      // layer 2 + LN
}